// Round 4
// baseline (399.583 us; speedup 1.0000x reference)
//
#include <hip/hip_runtime.h>
#include <stdint.h>

// VQ-VAE quantize forward, MI355X. Split-f16 MFMA distance GEMM.
// R4: BK=32 -> 33.8KB LDS -> 4 blocks/CU (was 2); fused split kernel.
// out = [values (BT*D)] [indexes as float (BT)] [loss (1)]

#define BT   65536      // 16*4096 rows
#define D    256        // codeword size
#define KCB  1024       // codebook size
#define BM   128        // rows per block tile
#define BN   128        // cols per n-tile
#define NT   (KCB/BN)   // 8 col tiles
#define BK   32         // k chunk (64B rows in LDS)

typedef float    f32x4 __attribute__((ext_vector_type(4)));
typedef _Float16 f16x8 __attribute__((ext_vector_type(8)));

#define GLOAD_LDS16(g, l) \
  __builtin_amdgcn_global_load_lds((const __attribute__((address_space(1))) void*)(g), \
                                   (__attribute__((address_space(3))) void*)(l), 16, 0, 0)

// ---- fused split: X -> Xh+Xl, E -> Eh+El + |e|^2 (one dispatch) ----
__global__ __launch_bounds__(256) void split_kernel(const float* __restrict__ X,
                                                    const float* __restrict__ E,
                                                    _Float16* __restrict__ Xh,
                                                    _Float16* __restrict__ Xl,
                                                    _Float16* __restrict__ Eh,
                                                    _Float16* __restrict__ El,
                                                    float* __restrict__ enorm) {
    const int b   = blockIdx.x;
    const int tid = threadIdx.x;
    if (b < 8192) {               // X part: 2048 elems/block
        const size_t i0 = ((size_t)b * 256 + tid) * 8;
        float4 v0 = *(const float4*)(X + i0);
        float4 v1 = *(const float4*)(X + i0 + 4);
        float v[8] = {v0.x, v0.y, v0.z, v0.w, v1.x, v1.y, v1.z, v1.w};
        f16x8 h, l;
        #pragma unroll
        for (int j = 0; j < 8; ++j) {
            _Float16 hh = (_Float16)v[j];
            h[j] = hh;
            l[j] = (_Float16)(v[j] - (float)hh);
        }
        *(f16x8*)(Xh + i0) = h;
        *(f16x8*)(Xl + i0) = l;
    } else {                      // E part: 8 rows/block, 32 threads/row
        const int r = (b - 8192) * 8 + (tid >> 5);
        const size_t i0 = (size_t)r * D + (tid & 31) * 8;
        float4 v0 = *(const float4*)(E + i0);
        float4 v1 = *(const float4*)(E + i0 + 4);
        float v[8] = {v0.x, v0.y, v0.z, v0.w, v1.x, v1.y, v1.z, v1.w};
        f16x8 h, l;
        float s = 0.f;
        #pragma unroll
        for (int j = 0; j < 8; ++j) {
            _Float16 hh = (_Float16)v[j];
            h[j] = hh;
            l[j] = (_Float16)(v[j] - (float)hh);
            s += v[j] * v[j];
        }
        *(f16x8*)(Eh + i0) = h;
        *(f16x8*)(El + i0) = l;
        #pragma unroll
        for (int off = 1; off < 32; off <<= 1) s += __shfl_xor(s, off, 64);
        if ((tid & 31) == 0) enorm[r] = s;
    }
}

// ---- main: fused 3-term split-f16 MFMA distance GEMM + argmin + gather + loss ----
// LDS rows are 64B (BK=32): 4 x 16B slots. Physical slot p at row r holds
// logical chunk c with p = (c + (r>>1)) & 3  -> ds_read phases spread 2-way (free),
// staging stays wave-uniform-base + lane*16 as global_load_lds requires.
__global__ __launch_bounds__(256, 4) void vq_mfma_kernel(
    const float* __restrict__ X, const float* __restrict__ E,
    const _Float16* __restrict__ Xh, const _Float16* __restrict__ Xl,
    const _Float16* __restrict__ Eh, const _Float16* __restrict__ El,
    const float* __restrict__ enorm,
    float* __restrict__ out_vals, float* __restrict__ out_idx,
    float* __restrict__ out_loss) {
    __shared__ __align__(16) _Float16 Ash[BM * BK];   // 8 KB each
    __shared__ __align__(16) _Float16 Asl[BM * BK];
    __shared__ __align__(16) _Float16 Bsh[BN * BK];
    __shared__ __align__(16) _Float16 Bsl[BN * BK];
    __shared__ float s_bd[BM];
    __shared__ int   s_bi[BM];
    __shared__ float s_red[4];

    const int tid  = threadIdx.x;
    const int w    = tid >> 6;
    const int lane = tid & 63;
    const int wm   = w >> 1;          // wave row (0..1)
    const int wn   = w & 1;           // wave col (0..1)
    const int quad = lane >> 4;
    const int l16  = lane & 15;
    const int row0 = blockIdx.x * BM;

    // staging: 8 chunks of 1KB per tile (16 rows each); wave w owns chunks w*2, w*2+1.
    // lane -> row chunk*16 + (lane>>2), physical slot lane&3,
    // global col chunk cg = ((lane&3) - ((lane>>3)&3)) & 3   [inverse of p=(c+(r>>1))&3]
    const int s_row = lane >> 2;
    const int cg    = ((lane & 3) - ((lane >> 3) & 3)) & 3;
    const int s_off = cg * 8;                 // f16 offset within the 32-k row
    // frag-read physical slot (same for all i,j since their row bases are mult of 16)
    const int ko = (((quad + ((l16 >> 1) & 3)) & 3)) * 8;

    float rb_d[4][4];
    int   rb_i[4][4];
    #pragma unroll
    for (int i = 0; i < 4; ++i)
        #pragma unroll
        for (int r = 0; r < 4; ++r) { rb_d[i][r] = 3.4e38f; rb_i[i][r] = 0; }

    for (int nt = 0; nt < NT; ++nt) {
        const int col0 = nt * BN;
        f32x4 acc[4][4];
        #pragma unroll
        for (int i = 0; i < 4; ++i)
            #pragma unroll
            for (int j = 0; j < 4; ++j) acc[i][j] = (f32x4)0.0f;

        for (int kc = 0; kc < D; kc += BK) {
            __syncthreads();      // previous tile fully consumed
            #pragma unroll
            for (int t = 0; t < 2; ++t) {
                const int chunk = w * 2 + t;
                const int r = chunk * 16 + s_row;
                const size_t ga = (size_t)(row0 + r) * D + kc + s_off;
                const size_t gb = (size_t)(col0 + r) * D + kc + s_off;
                GLOAD_LDS16(Xh + ga, &Ash[chunk * 512]);
                GLOAD_LDS16(Xl + ga, &Asl[chunk * 512]);
                GLOAD_LDS16(Eh + gb, &Bsh[chunk * 512]);
                GLOAD_LDS16(El + gb, &Bsl[chunk * 512]);
            }
            __syncthreads();      // waits vmcnt(0): staging landed
            f16x8 ah[4], al[4], bh[4], bl[4];
            #pragma unroll
            for (int i = 0; i < 4; ++i) {
                const int m = (wm * 64 + i * 16 + l16) * BK + ko;
                ah[i] = *(const f16x8*)&Ash[m];
                al[i] = *(const f16x8*)&Asl[m];
            }
            #pragma unroll
            for (int j = 0; j < 4; ++j) {
                const int n = (wn * 64 + j * 16 + l16) * BK + ko;
                bh[j] = *(const f16x8*)&Bsh[n];
                bl[j] = *(const f16x8*)&Bsl[n];
            }
            #pragma unroll
            for (int i = 0; i < 4; ++i)
                #pragma unroll
                for (int j = 0; j < 4; ++j) {
                    acc[i][j] = __builtin_amdgcn_mfma_f32_16x16x32_f16(ah[i], bh[j], acc[i][j], 0, 0, 0);
                    acc[i][j] = __builtin_amdgcn_mfma_f32_16x16x32_f16(al[i], bh[j], acc[i][j], 0, 0, 0);
                    acc[i][j] = __builtin_amdgcn_mfma_f32_16x16x32_f16(ah[i], bl[j], acc[i][j], 0, 0, 0);
                }
        }

        // score = |e|^2 - 2 x.e ; running per-lane argmin (cols ascend -> strict <)
        #pragma unroll
        for (int j = 0; j < 4; ++j) {
            const int c = col0 + wn * 64 + j * 16 + l16;
            const float en = enorm[c];
            #pragma unroll
            for (int i = 0; i < 4; ++i)
                #pragma unroll
                for (int r = 0; r < 4; ++r) {
                    const float s = en - 2.0f * acc[i][j][r];
                    if (s < rb_d[i][r]) { rb_d[i][r] = s; rb_i[i][r] = c; }
                }
        }
    }

    // fold the 16 lanes of each quad (they partition the wave's col slices)
    #pragma unroll
    for (int off = 1; off < 16; off <<= 1) {
        #pragma unroll
        for (int i = 0; i < 4; ++i)
            #pragma unroll
            for (int r = 0; r < 4; ++r) {
                const float od = __shfl_xor(rb_d[i][r], off, 64);
                const int   oi = __shfl_xor(rb_i[i][r], off, 64);
                if (od < rb_d[i][r] || (od == rb_d[i][r] && oi < rb_i[i][r])) {
                    rb_d[i][r] = od; rb_i[i][r] = oi;
                }
            }
    }
    // two-phase deterministic merge of the wn=0 / wn=1 halves
    if (wn == 0 && l16 == 0) {
        #pragma unroll
        for (int i = 0; i < 4; ++i)
            #pragma unroll
            for (int r = 0; r < 4; ++r) {
                const int m = wm * 64 + i * 16 + quad * 4 + r;
                s_bd[m] = rb_d[i][r]; s_bi[m] = rb_i[i][r];
            }
    }
    __syncthreads();
    if (wn == 1 && l16 == 0) {
        #pragma unroll
        for (int i = 0; i < 4; ++i)
            #pragma unroll
            for (int r = 0; r < 4; ++r) {
                const int m = wm * 64 + i * 16 + quad * 4 + r;
                if (rb_d[i][r] < s_bd[m] || (rb_d[i][r] == s_bd[m] && rb_i[i][r] < s_bi[m])) {
                    s_bd[m] = rb_d[i][r]; s_bi[m] = rb_i[i][r];
                }
            }
    }
    __syncthreads();

    // epilogue: gather values (straight-through fwd == values), loss partial
    float lsum = 0.f;
    for (int r = 0; r < BM; ++r) {
        const int row = row0 + r;
        const int bi  = s_bi[r];
        const float xv = X[(size_t)row * D + tid];
        const float ev = E[(size_t)bi * D + tid];
        out_vals[(size_t)row * D + tid] = ev;
        const float dd = xv - ev;
        lsum += dd * dd;
    }
    if (tid < BM) out_idx[row0 + tid] = (float)s_bi[tid];

    #pragma unroll
    for (int off = 1; off < 64; off <<= 1) lsum += __shfl_xor(lsum, off, 64);
    if (lane == 0) s_red[w] = lsum;
    __syncthreads();
    if (tid == 0) {
        const float total = s_red[0] + s_red[1] + s_red[2] + s_red[3];
        atomicAdd(out_loss, total * (1.1f / 16777216.f));  // loss1 + 0.1*loss2
    }
}

extern "C" void kernel_launch(void* const* d_in, const int* in_sizes, int n_in,
                              void* d_out, int out_size, void* d_ws, size_t ws_size,
                              hipStream_t stream) {
    const float* X = (const float*)d_in[0];
    const float* E = (const float*)d_in[1];
    float* out      = (float*)d_out;
    float* out_vals = out;
    float* out_idx  = out + (size_t)BT * D;
    float* out_loss = out + (size_t)BT * D + BT;

    char* ws = (char*)d_ws;
    _Float16* Xh = (_Float16*)ws;
    _Float16* Xl = Xh + (size_t)BT * D;
    _Float16* Eh = Xl + (size_t)BT * D;
    _Float16* El = Eh + (size_t)KCB * D;
    float*    enorm = (float*)(El + (size_t)KCB * D);
    (void)ws_size; (void)n_in; (void)in_sizes; (void)out_size;

    hipMemsetAsync(out_loss, 0, sizeof(float), stream);  // d_out poisoned 0xAA
    split_kernel<<<8192 + (KCB * D) / 2048, 256, 0, stream>>>(X, E, Xh, Xl, Eh, El, enorm);
    vq_mfma_kernel<<<BT / BM, 256, 0, stream>>>(X, E, Xh, Xl, Eh, El, enorm,
                                                out_vals, out_idx, out_loss);
}

// Round 5
// 245.329 us; speedup vs baseline: 1.6288x; 1.6288x over previous
//
#include <hip/hip_runtime.h>
#include <stdint.h>

// VQ-VAE quantize forward, MI355X. Split-f16 MFMA distance GEMM.
// R5: no X-split kernel — A staged as fp32 via global_load_lds, hi/lo f16
// split done in-register after ds_read (+8.5us aggregate VALU, hidden under
// MFMA). LDS 33KB, __launch_bounds__(256,3) -> 3 waves/SIMD (r4 showed the
// combined VGPR+AGPR cap = 512/waves; 4 waves spilled catastrophically).
// out = [values (BT*D)] [indexes as float (BT)] [loss (1)]

#define BT   65536      // 16*4096 rows
#define D    256        // codeword size
#define KCB  1024       // codebook size
#define BM   128        // rows per block tile
#define BN   128        // cols per n-tile
#define NT   (KCB/BN)   // 8 col tiles
#define BK   32         // k chunk

typedef float    f32x4 __attribute__((ext_vector_type(4)));
typedef _Float16 f16x8 __attribute__((ext_vector_type(8)));

#define GLOAD_LDS16(g, l) \
  __builtin_amdgcn_global_load_lds((const __attribute__((address_space(1))) void*)(g), \
                                   (__attribute__((address_space(3))) void*)(l), 16, 0, 0)

// ---- split E -> Eh, El + fp32 |e|^2 (1MB input; ~3us) ----
__global__ __launch_bounds__(256) void split_e_kernel(const float* __restrict__ E,
                                                      _Float16* __restrict__ Eh,
                                                      _Float16* __restrict__ El,
                                                      float* __restrict__ enorm) {
    const int r = blockIdx.x * 8 + (threadIdx.x >> 5);
    const size_t i0 = (size_t)r * D + (threadIdx.x & 31) * 8;
    float4 v0 = *(const float4*)(E + i0);
    float4 v1 = *(const float4*)(E + i0 + 4);
    float v[8] = {v0.x, v0.y, v0.z, v0.w, v1.x, v1.y, v1.z, v1.w};
    f16x8 h, l;
    float s = 0.f;
    #pragma unroll
    for (int j = 0; j < 8; ++j) {
        _Float16 hh = (_Float16)v[j];
        h[j] = hh;
        l[j] = (_Float16)(v[j] - (float)hh);
        s += v[j] * v[j];
    }
    *(f16x8*)(Eh + i0) = h;
    *(f16x8*)(El + i0) = l;
    #pragma unroll
    for (int off = 1; off < 32; off <<= 1) s += __shfl_xor(s, off, 64);
    if ((threadIdx.x & 31) == 0) enorm[r] = s;
}

// ---- main: fused 3-term split-f16 MFMA distance GEMM + argmin + gather + loss ----
// A tile: fp32, 128 rows x 32 k = 16KB; rows are 128B = 8 x 16B chunks,
// physical chunk p = c ^ (r&7)  (r3-verified: 0 conflicts).
// B tiles: f16 hi/lo, 64B rows = 4 x 16B slots, p = (c + (r>>1)) & 3
// (r4-verified: 0 conflicts). Staging stays wave-uniform-base + lane*16.
__global__ __launch_bounds__(256, 3) void vq_mfma_kernel(
    const float* __restrict__ X, const float* __restrict__ E,
    const _Float16* __restrict__ Eh, const _Float16* __restrict__ El,
    const float* __restrict__ enorm,
    float* __restrict__ out_vals, float* __restrict__ out_idx,
    float* __restrict__ out_loss) {
    __shared__ __align__(16) float    Asf[BM * BK];   // 16 KB fp32 A
    __shared__ __align__(16) _Float16 Bsh[BN * BK];   // 8 KB
    __shared__ __align__(16) _Float16 Bsl[BN * BK];   // 8 KB
    __shared__ float s_bd[BM];
    __shared__ int   s_bi[BM];
    __shared__ float s_red[4];

    const int tid  = threadIdx.x;
    const int w    = tid >> 6;
    const int lane = tid & 63;
    const int wm   = w >> 1;          // wave row (0..1)
    const int wn   = w & 1;           // wave col (0..1)
    const int quad = lane >> 4;
    const int l16  = lane & 15;
    const int row0 = blockIdx.x * BM;

    // A staging: 16 chunks of 1KB (8 fp32 rows each); wave w owns chunks w*4..w*4+3.
    // lane -> row chunk*8 + (lane>>3); phys slot lane&7; global 16B chunk (lane&7)^(lane>>3).
    const int sa_row = lane >> 3;
    const int sa_off = ((lane & 7) ^ sa_row) * 4;          // float offset in 32-k row
    // B staging: 8 chunks of 1KB (16 f16 rows each); wave w owns chunks w*2, w*2+1.
    const int sb_row = lane >> 2;
    const int sb_off = (((lane & 3) - ((lane >> 3) & 3)) & 3) * 8;  // f16 offset
    // B frag-read physical slot (row bases are multiples of 16 -> same for all j)
    const int kob = ((quad + ((l16 >> 1) & 3)) & 3) * 8;
    const int sxa = l16 & 7;                                // A frag-read row swizzle

    float rb_d[4][4];
    int   rb_i[4][4];
    #pragma unroll
    for (int i = 0; i < 4; ++i)
        #pragma unroll
        for (int r = 0; r < 4; ++r) { rb_d[i][r] = 3.4e38f; rb_i[i][r] = 0; }

    for (int nt = 0; nt < NT; ++nt) {
        const int col0 = nt * BN;
        f32x4 acc[4][4];
        #pragma unroll
        for (int i = 0; i < 4; ++i)
            #pragma unroll
            for (int j = 0; j < 4; ++j) acc[i][j] = (f32x4)0.0f;

        for (int kc = 0; kc < D; kc += BK) {
            __syncthreads();      // previous tile fully consumed
            #pragma unroll
            for (int t = 0; t < 4; ++t) {
                const int chunk = w * 4 + t;
                const int r = chunk * 8 + sa_row;
                GLOAD_LDS16(X + (size_t)(row0 + r) * D + kc + sa_off, &Asf[chunk * 256]);
            }
            #pragma unroll
            for (int t = 0; t < 2; ++t) {
                const int chunk = w * 2 + t;
                const int r = chunk * 16 + sb_row;
                const size_t gb = (size_t)(col0 + r) * D + kc + sb_off;
                GLOAD_LDS16(Eh + gb, &Bsh[chunk * 512]);
                GLOAD_LDS16(El + gb, &Bsl[chunk * 512]);
            }
            __syncthreads();      // waits vmcnt(0): staging landed

            // A frags: read fp32, split to f16 hi/lo in-register (once per kc)
            f16x8 ah[4], al[4];
            #pragma unroll
            for (int i = 0; i < 4; ++i) {
                const int ra = (wm * 64 + i * 16 + l16) * BK;
                f32x4 v0 = *(const f32x4*)&Asf[ra + ((((quad << 1))     ^ sxa) << 2)];
                f32x4 v1 = *(const f32x4*)&Asf[ra + ((((quad << 1) | 1) ^ sxa) << 2)];
                float f[8] = {v0.x, v0.y, v0.z, v0.w, v1.x, v1.y, v1.z, v1.w};
                #pragma unroll
                for (int e = 0; e < 8; ++e) {
                    _Float16 hh = (_Float16)f[e];
                    ah[i][e] = hh;
                    al[i][e] = (_Float16)(f[e] - (float)hh);
                }
            }
            // per-j b-frags (keeps live VGPRs under the 3-wave cap)
            #pragma unroll
            for (int j = 0; j < 4; ++j) {
                const int n = (wn * 64 + j * 16 + l16) * BK + kob;
                f16x8 bh = *(const f16x8*)&Bsh[n];
                f16x8 bl = *(const f16x8*)&Bsl[n];
                #pragma unroll
                for (int i = 0; i < 4; ++i) {
                    acc[i][j] = __builtin_amdgcn_mfma_f32_16x16x32_f16(ah[i], bh, acc[i][j], 0, 0, 0);
                    acc[i][j] = __builtin_amdgcn_mfma_f32_16x16x32_f16(al[i], bh, acc[i][j], 0, 0, 0);
                    acc[i][j] = __builtin_amdgcn_mfma_f32_16x16x32_f16(ah[i], bl, acc[i][j], 0, 0, 0);
                }
            }
        }

        // score = |e|^2 - 2 x.e ; running per-lane argmin (cols ascend -> strict <)
        #pragma unroll
        for (int j = 0; j < 4; ++j) {
            const int c = col0 + wn * 64 + j * 16 + l16;
            const float en = enorm[c];
            #pragma unroll
            for (int i = 0; i < 4; ++i)
                #pragma unroll
                for (int r = 0; r < 4; ++r) {
                    const float s = en - 2.0f * acc[i][j][r];
                    if (s < rb_d[i][r]) { rb_d[i][r] = s; rb_i[i][r] = c; }
                }
        }
    }

    // fold the 16 lanes of each quad (they partition the wave's col slices)
    #pragma unroll
    for (int off = 1; off < 16; off <<= 1) {
        #pragma unroll
        for (int i = 0; i < 4; ++i)
            #pragma unroll
            for (int r = 0; r < 4; ++r) {
                const float od = __shfl_xor(rb_d[i][r], off, 64);
                const int   oi = __shfl_xor(rb_i[i][r], off, 64);
                if (od < rb_d[i][r] || (od == rb_d[i][r] && oi < rb_i[i][r])) {
                    rb_d[i][r] = od; rb_i[i][r] = oi;
                }
            }
    }
    // two-phase deterministic merge of the wn=0 / wn=1 halves
    if (wn == 0 && l16 == 0) {
        #pragma unroll
        for (int i = 0; i < 4; ++i)
            #pragma unroll
            for (int r = 0; r < 4; ++r) {
                const int m = wm * 64 + i * 16 + quad * 4 + r;
                s_bd[m] = rb_d[i][r]; s_bi[m] = rb_i[i][r];
            }
    }
    __syncthreads();
    if (wn == 1 && l16 == 0) {
        #pragma unroll
        for (int i = 0; i < 4; ++i)
            #pragma unroll
            for (int r = 0; r < 4; ++r) {
                const int m = wm * 64 + i * 16 + quad * 4 + r;
                if (rb_d[i][r] < s_bd[m] || (rb_d[i][r] == s_bd[m] && rb_i[i][r] < s_bi[m])) {
                    s_bd[m] = rb_d[i][r]; s_bi[m] = rb_i[i][r];
                }
            }
    }
    __syncthreads();

    // epilogue: gather values (straight-through fwd == values), loss partial
    float lsum = 0.f;
    for (int r = 0; r < BM; ++r) {
        const int row = row0 + r;
        const int bi  = s_bi[r];
        const float xv = X[(size_t)row * D + tid];
        const float ev = E[(size_t)bi * D + tid];
        out_vals[(size_t)row * D + tid] = ev;
        const float dd = xv - ev;
        lsum += dd * dd;
    }
    if (tid < BM) out_idx[row0 + tid] = (float)s_bi[tid];

    #pragma unroll
    for (int off = 1; off < 64; off <<= 1) lsum += __shfl_xor(lsum, off, 64);
    if (lane == 0) s_red[w] = lsum;
    __syncthreads();
    if (tid == 0) {
        const float total = s_red[0] + s_red[1] + s_red[2] + s_red[3];
        atomicAdd(out_loss, total * (1.1f / 16777216.f));  // loss1 + 0.1*loss2
    }
}

extern "C" void kernel_launch(void* const* d_in, const int* in_sizes, int n_in,
                              void* d_out, int out_size, void* d_ws, size_t ws_size,
                              hipStream_t stream) {
    const float* X = (const float*)d_in[0];
    const float* E = (const float*)d_in[1];
    float* out      = (float*)d_out;
    float* out_vals = out;
    float* out_idx  = out + (size_t)BT * D;
    float* out_loss = out + (size_t)BT * D + BT;

    char* ws = (char*)d_ws;
    _Float16* Eh = (_Float16*)ws;
    _Float16* El = Eh + (size_t)KCB * D;
    float*    enorm = (float*)(El + (size_t)KCB * D);
    (void)ws_size; (void)n_in; (void)in_sizes; (void)out_size;

    hipMemsetAsync(out_loss, 0, sizeof(float), stream);  // d_out poisoned 0xAA
    split_e_kernel<<<KCB / 8, 256, 0, stream>>>(E, Eh, El, enorm);
    vq_mfma_kernel<<<BT / BM, 256, 0, stream>>>(X, E, Eh, El, enorm,
                                                out_vals, out_idx, out_loss);
}